// Round 14
// baseline (126.455 us; speedup 1.0000x reference)
//
#include <hip/hip_runtime.h>
#include <hip/hip_bf16.h>

#define D 64

typedef __attribute__((ext_vector_type(8))) short bf16x8;   // 8 bf16 (4 VGPRs)
typedef __attribute__((ext_vector_type(4))) float f32x4;    // MFMA C/D

__device__ __forceinline__ float bf2f(unsigned short u) {
    return __uint_as_float(((unsigned)u) << 16);
}
__device__ __forceinline__ unsigned short f2bf(float f) {
    __hip_bfloat16 b = __float2bfloat16(f);        // RN
    return *(unsigned short*)&b;
}

// ---- prep: zero cnt + x->bf16 SPLIT halves + W->bf16 ------------------------
// x stored as two [N,32] arrays (64B rows): each gather pass's hot set is
// 3.2MB -> fits a 4MB per-XCD L2 (the round-14 structural bet).

__global__ void prep_k(const float* __restrict__ x,
                       unsigned short* __restrict__ xbA, unsigned short* __restrict__ xbB,
                       const float* __restrict__ Wl1, const float* __restrict__ Wr1,
                       const float* __restrict__ Wl2, const float* __restrict__ Wr2,
                       unsigned short* __restrict__ Wbf,
                       int* __restrict__ cnt, int n4, int ncnt4) {
    int i = blockIdx.x * blockDim.x + threadIdx.x;
    if (i < n4) {                                  // float4 quad q of node n
        float4 v = ((const float4*)x)[i];
        int n = i >> 4, q = i & 15;
        ushort4 u;
        u.x = f2bf(v.x); u.y = f2bf(v.y); u.z = f2bf(v.z); u.w = f2bf(v.w);
        if (q < 8) *(ushort4*)(xbA + (size_t)n * 32 + q * 4) = u;
        else       *(ushort4*)(xbB + (size_t)n * 32 + (q - 8) * 4) = u;
    }
    if (i < ncnt4) ((int4*)cnt)[i] = make_int4(0, 0, 0, 0);
    if (i < 4096) {                                // 4 x [64,64] weights
        Wbf[i]           = f2bf(Wl1[i]);
        Wbf[4096 + i]    = f2bf(Wr1[i]);
        Wbf[8192 + i]    = f2bf(Wl2[i]);
        Wbf[12288 + i]   = f2bf(Wr2[i]);
    }
}

// ---- CSR build (no scanC; consumers add bsum[chunk] on the fly) -------------

__global__ void pos_k(const int* __restrict__ dst, int* __restrict__ cnt,
                      unsigned short* __restrict__ pos, int E) {
    int e0 = (blockIdx.x * blockDim.x + threadIdx.x) * 4;
    if (e0 + 4 <= E) {
        int4 d = *(const int4*)(dst + e0);
        int px = atomicAdd(&cnt[d.x], 1);
        int py = atomicAdd(&cnt[d.y], 1);
        int pz = atomicAdd(&cnt[d.z], 1);
        int pw = atomicAdd(&cnt[d.w], 1);
        *(ushort4*)(pos + e0) = make_ushort4((unsigned short)px, (unsigned short)py,
                                             (unsigned short)pz, (unsigned short)pw);
    } else {
        for (int e = e0; e < E; ++e)
            pos[e] = (unsigned short)atomicAdd(&cnt[dst[e]], 1);
    }
}

__global__ void scanA_k(const int* __restrict__ cnt, int* __restrict__ rowptrL,
                        int* __restrict__ bsum, int N) {
    __shared__ int tmp[256];
    int gid = blockIdx.x * 256 + threadIdx.x;
    int v = (gid < N) ? cnt[gid] : 0;
    tmp[threadIdx.x] = v;
    __syncthreads();
    for (int off = 1; off < 256; off <<= 1) {
        int t = (threadIdx.x >= off) ? tmp[threadIdx.x - off] : 0;
        __syncthreads();
        tmp[threadIdx.x] += t;
        __syncthreads();
    }
    if (gid < N) rowptrL[gid] = tmp[threadIdx.x] - v;  // exclusive within chunk
    if (threadIdx.x == 255) bsum[blockIdx.x] = tmp[255];
}

__global__ void scanB_k(int* __restrict__ bsum, int nb) {  // nb <= 256
    __shared__ int tmp[256];
    int v = (threadIdx.x < nb) ? bsum[threadIdx.x] : 0;
    tmp[threadIdx.x] = v;
    __syncthreads();
    for (int off = 1; off < 256; off <<= 1) {
        int t = (threadIdx.x >= off) ? tmp[threadIdx.x - off] : 0;
        __syncthreads();
        tmp[threadIdx.x] += t;
        __syncthreads();
    }
    if (threadIdx.x < nb) bsum[threadIdx.x] = tmp[threadIdx.x] - v;  // exclusive
}

__global__ void fill2_k(const int* __restrict__ src, const int* __restrict__ dst,
                        const unsigned short* __restrict__ pos,
                        const int* __restrict__ rowptrL, const int* __restrict__ bsum,
                        unsigned short* __restrict__ col, int E) {
    int e0 = (blockIdx.x * blockDim.x + threadIdx.x) * 4;
    if (e0 + 4 <= E) {
        int4 d = *(const int4*)(dst + e0);
        int4 s = *(const int4*)(src + e0);
        ushort4 p = *(const ushort4*)(pos + e0);
        col[rowptrL[d.x] + bsum[d.x >> 8] + p.x] = (unsigned short)s.x;
        col[rowptrL[d.y] + bsum[d.y >> 8] + p.y] = (unsigned short)s.y;
        col[rowptrL[d.z] + bsum[d.z >> 8] + p.z] = (unsigned short)s.z;
        col[rowptrL[d.w] + bsum[d.w >> 8] + p.w] = (unsigned short)s.w;
    } else {
        for (int e = e0; e < E; ++e)
            col[rowptrL[dst[e]] + bsum[dst[e] >> 8] + pos[e]] = (unsigned short)src[e];
    }
}

// ---- pass A: gather-mean of half A (features 0..31) -------------------------
// 8 lanes/node (ushort4 = 8B), 8 nodes/wave, 8 slots -> 64 lines in flight.
// Hot set xbA = 3.2MB: per-XCD-L2 resident across this whole dispatch.

__global__ __launch_bounds__(256) void aggA_k(
    const unsigned short* __restrict__ xbA,
    const int* __restrict__ rowptrL, const int* __restrict__ bsum,
    const unsigned short* __restrict__ col,
    unsigned short* __restrict__ aggbA, int N, int E)
{
    const int tid = threadIdx.x;
    const int idx = tid & 7;                       // lane-within-node
    const int n   = blockIdx.x * 32 + (tid >> 3);  // 32 nodes/block
    if (n >= N) return;
    const int beg = rowptrL[n] + bsum[n >> 8];
    const int end = (n + 1 < N) ? (rowptrL[n + 1] + bsum[(n + 1) >> 8]) : E;

    float ax[8], ay[8], az[8], aw[8];
    #pragma unroll
    for (int s = 0; s < 8; ++s) { ax[s]=0.f; ay[s]=0.f; az[s]=0.f; aw[s]=0.f; }
    for (int j = beg; j < end; j += 8) {           // clamp-predicated
        #pragma unroll
        for (int s = 0; s < 8; ++s) {
            int jj = j + s;
            float m = (jj < end) ? 1.f : 0.f;
            jj = (jj < end) ? jj : end - 1;
            int c = col[jj];
            ushort4 u = *(const ushort4*)(xbA + (size_t)c * 32 + idx * 4);
            ax[s] = fmaf(m, bf2f(u.x), ax[s]);
            ay[s] = fmaf(m, bf2f(u.y), ay[s]);
            az[s] = fmaf(m, bf2f(u.z), az[s]);
            aw[s] = fmaf(m, bf2f(u.w), aw[s]);
        }
    }
    float sx = ((ax[0]+ax[1])+(ax[2]+ax[3]))+((ax[4]+ax[5])+(ax[6]+ax[7]));
    float sy = ((ay[0]+ay[1])+(ay[2]+ay[3]))+((ay[4]+ay[5])+(ay[6]+ay[7]));
    float sz = ((az[0]+az[1])+(az[2]+az[3]))+((az[4]+az[5])+(az[6]+az[7]));
    float sw = ((aw[0]+aw[1])+(aw[2]+aw[3]))+((aw[4]+aw[5])+(aw[6]+aw[7]));
    const float inv = 1.0f / fmaxf((float)(end - beg), 1.0f);
    ushort4 o;
    o.x = f2bf(sx*inv); o.y = f2bf(sy*inv); o.z = f2bf(sz*inv); o.w = f2bf(sw*inv);
    *(ushort4*)(aggbA + (size_t)n * 32 + idx * 4) = o;
}

// ---- pass B + MLP: gather half B, combine with pass-A means, MFMA -----------
// Gather-B: 16 lanes/node (ushort2 = 4B), rows 64B, hot set xbB = 3.2MB.
// sagg[16][72]: cols 0..31 from aggbA (streamed), 32..63 from gather-B.
// MFMA frag split: kc=0 k-range [0,32) = half A; kc=1 = [32,64) = half B.
// C/D: col=lane&15, row=(lane>>4)*4+reg (verified m89 layout).

__device__ __forceinline__ float tanh_fast(float v) {
    float e = __expf(2.f * v);                     // inf-safe at extremes
    return 1.f - 2.f * __builtin_amdgcn_rcpf(e + 1.f);
}

template <int TANH>
__global__ __launch_bounds__(256) void layerB_k(
    const unsigned short* __restrict__ xbA,        // [N,32] self-term half A
    const unsigned short* __restrict__ xbB,        // [N,32] gather + self half B
    const unsigned short* __restrict__ aggbA,      // [N,32] pass-A means
    const int* __restrict__ rowptrL, const int* __restrict__ bsum,
    const unsigned short* __restrict__ col,
    const unsigned short* __restrict__ Wlb,        // [64,64] bf16, [f][k]
    const unsigned short* __restrict__ Wrb,
    const float* __restrict__ bias,
    float* __restrict__ outf,                      // TANH=0: fp32 final
    unsigned short* __restrict__ houtA,            // TANH=1: h halves
    unsigned short* __restrict__ houtB,
    int N, int E)
{
    __shared__ unsigned short sagg[16][72];        // 2.3KB, stride 144B
    const int tid = threadIdx.x;
    const int n0  = blockIdx.x * 16;               // N%16==0: all nodes valid

    // pass-A means for this block's nodes -> regs (sequential, 1KB)
    ushort4 aA;
    if (tid < 128) aA = *(const ushort4*)(aggbA + (size_t)(n0 + (tid >> 3)) * 32 + (tid & 7) * 4);

    // gather half B
    const int idx = tid & 15;                      // lane-within-node
    const int nl  = tid >> 4;
    const int n   = n0 + nl;
    const int beg = rowptrL[n] + bsum[n >> 8];
    const int end = (n + 1 < N) ? (rowptrL[n + 1] + bsum[(n + 1) >> 8]) : E;
    float ax[8], ay[8];
    #pragma unroll
    for (int s = 0; s < 8; ++s) { ax[s] = 0.f; ay[s] = 0.f; }
    for (int j = beg; j < end; j += 8) {           // clamp-predicated
        #pragma unroll
        for (int s = 0; s < 8; ++s) {
            int jj = j + s;
            float m = (jj < end) ? 1.f : 0.f;
            jj = (jj < end) ? jj : end - 1;
            int c = col[jj];
            ushort2 u = *(const ushort2*)(xbB + (size_t)c * 32 + idx * 2);
            ax[s] = fmaf(m, bf2f(u.x), ax[s]);
            ay[s] = fmaf(m, bf2f(u.y), ay[s]);
        }
    }
    float sx = ((ax[0]+ax[1])+(ax[2]+ax[3]))+((ax[4]+ax[5])+(ax[6]+ax[7]));
    float sy = ((ay[0]+ay[1])+(ay[2]+ay[3]))+((ay[4]+ay[5])+(ay[6]+ay[7]));
    const float inv = 1.0f / fmaxf((float)(end - beg), 1.0f);
    ushort2 ob;
    ob.x = f2bf(sx * inv); ob.y = f2bf(sy * inv);

    if (tid < 128) *(ushort4*)&sagg[tid >> 3][(tid & 7) * 4] = aA;
    *(ushort2*)&sagg[nl][32 + idx * 2] = ob;
    __syncthreads();

    // MFMA: wave wid owns f-slice [16wid, 16wid+16)
    const int lane = tid & 63;
    const int wid  = tid >> 6;
    const int fr   = lane & 15;
    const int k0   = (lane >> 4) * 8;              // 0,8,16,24
    const int f    = wid * 16 + fr;

    bf16x8 bl[2], br[2];
    {
        const unsigned short* pl = Wlb + f * 64 + k0;
        const unsigned short* pr = Wrb + f * 64 + k0;
        #pragma unroll
        for (int kc = 0; kc < 2; ++kc) {
            bl[kc] = *(const bf16x8*)(pl + kc * 32);
            br[kc] = *(const bf16x8*)(pr + kc * 32);
        }
    }
    float bv = bias[f];
    f32x4 acc = (f32x4){bv, bv, bv, bv};

    bf16x8 aa[2], axf[2];
    aa[0] = *(const bf16x8*)&sagg[fr][k0];         // k in [0,32): half A
    aa[1] = *(const bf16x8*)&sagg[fr][32 + k0];    // k in [32,64): half B
    axf[0] = *(const bf16x8*)(xbA + (size_t)(n0 + fr) * 32 + k0);
    axf[1] = *(const bf16x8*)(xbB + (size_t)(n0 + fr) * 32 + k0);

    #pragma unroll
    for (int kc = 0; kc < 2; ++kc) {
        acc = __builtin_amdgcn_mfma_f32_16x16x32_bf16(aa[kc],  bl[kc], acc, 0, 0, 0);
        acc = __builtin_amdgcn_mfma_f32_16x16x32_bf16(axf[kc], br[kc], acc, 0, 0, 0);
    }

    const int rbase = n0 + (lane >> 4) * 4;        // D-row (node) base
    #pragma unroll
    for (int r = 0; r < 4; ++r) {
        int node = rbase + r;
        float v = acc[r];
        if (TANH) {
            v = tanh_fast(v);
            if (f < 32) houtA[(size_t)node * 32 + f]        = f2bf(v);
            else        houtB[(size_t)node * 32 + (f - 32)] = f2bf(v);
        } else {
            outf[(size_t)node * D + f] = v;
        }
    }
}

// ---- launcher ---------------------------------------------------------------

extern "C" void kernel_launch(void* const* d_in, const int* in_sizes, int n_in,
                              void* d_out, int out_size, void* d_ws, size_t ws_size,
                              hipStream_t stream) {
    const float* x   = (const float*)d_in[0];
    const int*   ei  = (const int*)d_in[1];     // int64 in ref -> int32 here
    const float* Wl1 = (const float*)d_in[2];
    const float* bl1 = (const float*)d_in[3];
    const float* Wr1 = (const float*)d_in[4];
    const float* Wl2 = (const float*)d_in[5];
    const float* bl2 = (const float*)d_in[6];
    const float* Wr2 = (const float*)d_in[7];

    const int N = in_sizes[0] / D;
    const int E = in_sizes[1] / 2;
    const int* srcI = ei;        // edge_index[0]
    const int* dstI = ei + E;    // edge_index[1]

    auto al = [](size_t v) { return (v + 255) & ~(size_t)255; };
    char* w = (char*)d_ws;
    size_t off = 0;
    int*            cnt     = (int*)(w + off);            off += al((size_t)N * 4);
    int*            rowptrL = (int*)(w + off);            off += al((size_t)N * 4);
    int*            bsum    = (int*)(w + off);            off += al(1024);
    unsigned short* colA    = (unsigned short*)(w + off); off += al((size_t)E * 2);
    unsigned short* pos     = (unsigned short*)(w + off); off += al((size_t)E * 2);
    unsigned short* xbA     = (unsigned short*)(w + off); off += al((size_t)N * 32 * 2);
    unsigned short* xbB     = (unsigned short*)(w + off); off += al((size_t)N * 32 * 2);
    unsigned short* hbA     = (unsigned short*)(w + off); off += al((size_t)N * 32 * 2);
    unsigned short* hbB     = (unsigned short*)(w + off); off += al((size_t)N * 32 * 2);
    unsigned short* aggbA   = (unsigned short*)(w + off); off += al((size_t)N * 32 * 2);
    unsigned short* Wbf     = (unsigned short*)(w + off); off += al((size_t)4 * D * D * 2);
    unsigned short* Wb_l1 = Wbf, *Wb_r1 = Wbf + D*D, *Wb_l2 = Wbf + 2*D*D, *Wb_r2 = Wbf + 3*D*D;

    float* out = (float*)d_out;

    const int NB  = (N + 255) / 256;         // 196 <= 256, scanB handles it
    const int EB4 = (E / 4 + 255) / 256;     // int4 edge kernels
    const int PB  = (N * D / 4 + 255) / 256; // prep: covers cvt-x (largest job)
    const int GA  = (N + 31) / 32;           // aggA_k: 32 nodes/block
    const int LB  = (N + 15) / 16;           // layerB_k: 16 nodes/block

    prep_k<<<PB, 256, 0, stream>>>(x, xbA, xbB, Wl1, Wr1, Wl2, Wr2, Wbf,
                                   cnt, N * D / 4, (N + 3) / 4);
    pos_k<<<EB4, 256, 0, stream>>>(dstI, cnt, pos, E);
    scanA_k<<<NB, 256, 0, stream>>>(cnt, rowptrL, bsum, N);
    scanB_k<<<1, 256, 0, stream>>>(bsum, NB);
    fill2_k<<<EB4, 256, 0, stream>>>(srcI, dstI, pos, rowptrL, bsum, colA, E);

    // layer 1: pass-A gather (xbA hot) ; pass-B gather + MFMA -> h halves
    aggA_k<<<GA, 256, 0, stream>>>(xbA, rowptrL, bsum, colA, aggbA, N, E);
    layerB_k<1><<<LB, 256, 0, stream>>>(xbA, xbB, aggbA, rowptrL, bsum, colA,
                                        Wb_l1, Wb_r1, bl1, nullptr, hbA, hbB, N, E);
    // layer 2: same over h halves -> fp32 out
    aggA_k<<<GA, 256, 0, stream>>>(hbA, rowptrL, bsum, colA, aggbA, N, E);
    layerB_k<0><<<LB, 256, 0, stream>>>(hbA, hbB, aggbA, rowptrL, bsum, colA,
                                        Wb_l2, Wb_r2, bl2, out, nullptr, nullptr, N, E);
}

// Round 15
// 125.023 us; speedup vs baseline: 1.0115x; 1.0115x over previous
//
#include <hip/hip_runtime.h>
#include <hip/hip_bf16.h>

#define D 64

typedef __attribute__((ext_vector_type(8))) short bf16x8;   // 8 bf16 (4 VGPRs)
typedef __attribute__((ext_vector_type(4))) float f32x4;    // MFMA C/D

__device__ __forceinline__ float bf2f(unsigned short u) {
    return __uint_as_float(((unsigned)u) << 16);
}
__device__ __forceinline__ unsigned short f2bf(float f) {
    __hip_bfloat16 b = __float2bfloat16(f);        // RN
    return *(unsigned short*)&b;
}

// ---- prep: zero cnt+done + x->bf16 + W->bf16, one streaming kernel ----------

__global__ void prep_k(const float* __restrict__ x, unsigned short* __restrict__ xbf,
                       const float* __restrict__ Wl1, const float* __restrict__ Wr1,
                       const float* __restrict__ Wl2, const float* __restrict__ Wr2,
                       unsigned short* __restrict__ Wbf,
                       int* __restrict__ cnt, int* __restrict__ done,
                       int n4, int ncnt4) {
    int i = blockIdx.x * blockDim.x + threadIdx.x;
    if (i < n4) {                                  // x: 4 floats -> 4 bf16
        float4 v = ((const float4*)x)[i];
        ushort4 u;
        u.x = f2bf(v.x); u.y = f2bf(v.y); u.z = f2bf(v.z); u.w = f2bf(v.w);
        ((ushort4*)xbf)[i] = u;
    }
    if (i < ncnt4) ((int4*)cnt)[i] = make_int4(0, 0, 0, 0);
    if (i == 0) *done = 0;
    if (i < 4096) {                                // 4 x [64,64] weights
        Wbf[i]           = f2bf(Wl1[i]);
        Wbf[4096 + i]    = f2bf(Wr1[i]);
        Wbf[8192 + i]    = f2bf(Wl2[i]);
        Wbf[12288 + i]   = f2bf(Wr2[i]);
    }
}

// ---- CSR build (no scanC; consumers add bsum[chunk] on the fly) -------------
// pos_k: atomic returns feed only SEQUENTIAL streaming stores (ushort: deg<64).

__global__ void pos_k(const int* __restrict__ dst, int* __restrict__ cnt,
                      unsigned short* __restrict__ pos, int E) {
    int e0 = (blockIdx.x * blockDim.x + threadIdx.x) * 4;
    if (e0 + 4 <= E) {
        int4 d = *(const int4*)(dst + e0);
        int px = atomicAdd(&cnt[d.x], 1);
        int py = atomicAdd(&cnt[d.y], 1);
        int pz = atomicAdd(&cnt[d.z], 1);
        int pw = atomicAdd(&cnt[d.w], 1);
        *(ushort4*)(pos + e0) = make_ushort4((unsigned short)px, (unsigned short)py,
                                             (unsigned short)pz, (unsigned short)pw);
    } else {
        for (int e = e0; e < E; ++e)
            pos[e] = (unsigned short)atomicAdd(&cnt[dst[e]], 1);
    }
}

// Block-local exclusive scan; block total -> bsum[b] (device-scope atomic).
// The LAST block to finish (done counter) exclusive-scans bsum in place.
// No spinning, no dispatch-order assumption (G16-safe: atomics are
// device-scope coherent across XCDs).
__global__ void scanAB_k(const int* __restrict__ cnt, int* __restrict__ rowptrL,
                         int* __restrict__ bsum, int* __restrict__ done,
                         int N, int NB) {
    __shared__ int tmp[256];
    __shared__ int islast;
    int gid = blockIdx.x * 256 + threadIdx.x;
    int v = (gid < N) ? cnt[gid] : 0;
    tmp[threadIdx.x] = v;
    __syncthreads();
    for (int off = 1; off < 256; off <<= 1) {
        int t = (threadIdx.x >= off) ? tmp[threadIdx.x - off] : 0;
        __syncthreads();
        tmp[threadIdx.x] += t;
        __syncthreads();
    }
    if (gid < N) rowptrL[gid] = tmp[threadIdx.x] - v;  // exclusive within chunk
    if (threadIdx.x == 255) {
        atomicExch(&bsum[blockIdx.x], tmp[255]);       // device-scope publish
        __threadfence();
        int prev = atomicAdd(done, 1);
        islast = (prev == NB - 1) ? 1 : 0;
    }
    __syncthreads();
    if (islast) {                                      // final 196-entry scan
        int b = (threadIdx.x < NB) ? atomicAdd(&bsum[threadIdx.x], 0) : 0;
        tmp[threadIdx.x] = b;
        __syncthreads();
        for (int off = 1; off < 256; off <<= 1) {
            int t = (threadIdx.x >= off) ? tmp[threadIdx.x - off] : 0;
            __syncthreads();
            tmp[threadIdx.x] += t;
            __syncthreads();
        }
        if (threadIdx.x < NB)
            atomicExch(&bsum[threadIdx.x], tmp[threadIdx.x] - b);  // exclusive
    }
}

// Scatter src ids as USHORT; rowptr reconstructed as rowptrL[d]+bsum[d>>8]
// (bsum = 784B, L1-resident). No atomics; stores fire-and-forget.
__global__ void fill2_k(const int* __restrict__ src, const int* __restrict__ dst,
                        const unsigned short* __restrict__ pos,
                        const int* __restrict__ rowptrL, const int* __restrict__ bsum,
                        unsigned short* __restrict__ col, int E) {
    int e0 = (blockIdx.x * blockDim.x + threadIdx.x) * 4;
    if (e0 + 4 <= E) {
        int4 d = *(const int4*)(dst + e0);
        int4 s = *(const int4*)(src + e0);
        ushort4 p = *(const ushort4*)(pos + e0);
        col[rowptrL[d.x] + bsum[d.x >> 8] + p.x] = (unsigned short)s.x;
        col[rowptrL[d.y] + bsum[d.y >> 8] + p.y] = (unsigned short)s.y;
        col[rowptrL[d.z] + bsum[d.z >> 8] + p.z] = (unsigned short)s.z;
        col[rowptrL[d.w] + bsum[d.w >> 8] + p.w] = (unsigned short)s.w;
    } else {
        for (int e = e0; e < E; ++e)
            col[rowptrL[dst[e]] + bsum[dst[e] >> 8] + pos[e]] = (unsigned short)src[e];
    }
}

// ---- fused layer: gather-mean (4 nodes/wave) + MFMA MLP ---------------------
// Gather loop is clamp-predicated: every node takes exactly ceil(deg/8)
// fully-parallel latency rounds; clamped duplicate loads hit the just-fetched
// line (cache hit, ~free). Mean -> LDS tile -> wave w computes f-slice
// [16w,16w+16) with 4 MFMAs. C/D: col=lane&15, row=(lane>>4)*4+reg (m89).

__device__ __forceinline__ float tanh_fast(float v) {
    float e = __expf(2.f * v);                     // inf-safe at extremes
    return 1.f - 2.f * __builtin_amdgcn_rcpf(e + 1.f);
}

template <int TANH>
__global__ __launch_bounds__(256) void layer_k(
    const unsigned short* __restrict__ xb,         // [N,64] bf16 (x or h)
    const int* __restrict__ rowptrL, const int* __restrict__ bsum,
    const unsigned short* __restrict__ col,
    const unsigned short* __restrict__ Wlb,        // [64,64] bf16, [f][k]
    const unsigned short* __restrict__ Wrb,
    const float* __restrict__ bias,
    float* __restrict__ outf, unsigned short* __restrict__ outb, int N, int E)
{
    __shared__ unsigned short sagg[16][72];        // 2.3KB, stride 144B
    const int tid = threadIdx.x;
    const int idx = tid & 15;                      // lane-within-node
    const int nl  = tid >> 4;                      // block-local node 0..15
    const int n0  = blockIdx.x * 16;
    const int n   = n0 + nl;

    // ---- phase 1: gather mean ----
    if (n < N) {
        const int beg = rowptrL[n] + bsum[n >> 8];
        const int end = (n + 1 < N) ? (rowptrL[n + 1] + bsum[(n + 1) >> 8]) : E;
        float ax[8], ay[8], az[8], aw[8];
        #pragma unroll
        for (int s = 0; s < 8; ++s) { ax[s]=0.f; ay[s]=0.f; az[s]=0.f; aw[s]=0.f; }
        for (int j = beg; j < end; j += 8) {       // clamp-predicated 8 slots
            #pragma unroll
            for (int s = 0; s < 8; ++s) {
                int jj = j + s;
                float m = (jj < end) ? 1.f : 0.f;
                jj = (jj < end) ? jj : end - 1;    // deg>=1 here (beg<end)
                int c = col[jj];
                ushort4 u = *(const ushort4*)(xb + (size_t)c * D + idx * 4);
                ax[s] = fmaf(m, bf2f(u.x), ax[s]);
                ay[s] = fmaf(m, bf2f(u.y), ay[s]);
                az[s] = fmaf(m, bf2f(u.z), az[s]);
                aw[s] = fmaf(m, bf2f(u.w), aw[s]);
            }
        }
        float sx = ((ax[0]+ax[1])+(ax[2]+ax[3]))+((ax[4]+ax[5])+(ax[6]+ax[7]));
        float sy = ((ay[0]+ay[1])+(ay[2]+ay[3]))+((ay[4]+ay[5])+(ay[6]+ay[7]));
        float sz = ((az[0]+az[1])+(az[2]+az[3]))+((az[4]+az[5])+(az[6]+az[7]));
        float sw = ((aw[0]+aw[1])+(aw[2]+aw[3]))+((aw[4]+aw[5])+(aw[6]+aw[7]));
        const float inv = 1.0f / fmaxf((float)(end - beg), 1.0f);
        ushort4 o;
        o.x = f2bf(sx*inv); o.y = f2bf(sy*inv); o.z = f2bf(sz*inv); o.w = f2bf(sw*inv);
        *(ushort4*)&sagg[nl][idx * 4] = o;
    } else {
        *(ushort4*)&sagg[nl][idx * 4] = make_ushort4(0, 0, 0, 0);
    }
    __syncthreads();

    // ---- phase 2: MFMA, wave wid owns f-slice [wid*16, wid*16+16) ----
    const int lane = tid & 63;
    const int wid  = tid >> 6;
    const int fr   = lane & 15;
    const int k0   = (lane >> 4) * 8;
    const int f    = wid * 16 + fr;

    bf16x8 bl[2], br[2];
    {
        const unsigned short* pl = Wlb + f * 64 + k0;
        const unsigned short* pr = Wrb + f * 64 + k0;
        #pragma unroll
        for (int kc = 0; kc < 2; ++kc) {
            bl[kc] = *(const bf16x8*)(pl + kc * 32);
            br[kc] = *(const bf16x8*)(pr + kc * 32);
        }
    }
    float bv = bias[f];
    f32x4 acc = (f32x4){bv, bv, bv, bv};

    bf16x8 aa[2], axf[2];
    #pragma unroll
    for (int kc = 0; kc < 2; ++kc)
        aa[kc] = *(const bf16x8*)&sagg[fr][kc * 32 + k0];
    {
        const unsigned short* px = xb + (size_t)(n0 + fr) * D + k0;  // n0+fr<N (N%16==0)
        #pragma unroll
        for (int kc = 0; kc < 2; ++kc)
            axf[kc] = *(const bf16x8*)(px + kc * 32);
    }

    #pragma unroll
    for (int kc = 0; kc < 2; ++kc) {
        acc = __builtin_amdgcn_mfma_f32_16x16x32_bf16(aa[kc],  bl[kc], acc, 0, 0, 0);
        acc = __builtin_amdgcn_mfma_f32_16x16x32_bf16(axf[kc], br[kc], acc, 0, 0, 0);
    }

    const int rbase = n0 + (lane >> 4) * 4;        // D-row (node) base
    #pragma unroll
    for (int r = 0; r < 4; ++r) {
        int node = rbase + r;
        if (node < N) {
            float v = acc[r];
            if (TANH) {
                v = tanh_fast(v);
                outb[(size_t)node * D + f] = f2bf(v);
            } else {
                outf[(size_t)node * D + f] = v;
            }
        }
    }
}

// ---- launcher ---------------------------------------------------------------

extern "C" void kernel_launch(void* const* d_in, const int* in_sizes, int n_in,
                              void* d_out, int out_size, void* d_ws, size_t ws_size,
                              hipStream_t stream) {
    const float* x   = (const float*)d_in[0];
    const int*   ei  = (const int*)d_in[1];     // int64 in ref -> int32 here
    const float* Wl1 = (const float*)d_in[2];
    const float* bl1 = (const float*)d_in[3];
    const float* Wr1 = (const float*)d_in[4];
    const float* Wl2 = (const float*)d_in[5];
    const float* bl2 = (const float*)d_in[6];
    const float* Wr2 = (const float*)d_in[7];

    const int N = in_sizes[0] / D;
    const int E = in_sizes[1] / 2;
    const int* srcI = ei;        // edge_index[0]
    const int* dstI = ei + E;    // edge_index[1]

    auto al = [](size_t v) { return (v + 255) & ~(size_t)255; };
    char* w = (char*)d_ws;
    size_t off = 0;
    int*            cnt     = (int*)(w + off);            off += al((size_t)N * 4);
    int*            rowptrL = (int*)(w + off);            off += al((size_t)N * 4);
    int*            bsum    = (int*)(w + off);            off += al(1024);
    int*            done    = (int*)(w + off);            off += al(256);
    unsigned short* colA    = (unsigned short*)(w + off); off += al((size_t)E * 2);
    unsigned short* pos     = (unsigned short*)(w + off); off += al((size_t)E * 2);
    unsigned short* xbf     = (unsigned short*)(w + off); off += al((size_t)N * D * 2);
    unsigned short* hbf     = (unsigned short*)(w + off); off += al((size_t)N * D * 2);
    unsigned short* Wbf     = (unsigned short*)(w + off); off += al((size_t)4 * D * D * 2);
    unsigned short* Wb_l1 = Wbf, *Wb_r1 = Wbf + D*D, *Wb_l2 = Wbf + 2*D*D, *Wb_r2 = Wbf + 3*D*D;

    float* out = (float*)d_out;

    const int NB  = (N + 255) / 256;         // 196 <= 256: scanAB last block ok
    const int EB4 = (E / 4 + 255) / 256;     // int4 edge kernels
    const int PB  = (N * D / 4 + 255) / 256; // prep: covers cvt-x (largest job)
    const int LB  = (N + 15) / 16;           // layer_k: 16 nodes/block

    prep_k<<<PB, 256, 0, stream>>>(x, xbf, Wl1, Wr1, Wl2, Wr2, Wbf,
                                   cnt, done, N * D / 4, (N + 3) / 4);
    pos_k<<<EB4, 256, 0, stream>>>(dstI, cnt, pos, E);
    scanAB_k<<<NB, 256, 0, stream>>>(cnt, rowptrL, bsum, done, N, NB);
    fill2_k<<<EB4, 256, 0, stream>>>(srcI, dstI, pos, rowptrL, bsum, colA, E);

    // layer 1: fused gather+MLP over x -> h (bf16)
    layer_k<1><<<LB, 256, 0, stream>>>(xbf, rowptrL, bsum, colA, Wb_l1, Wb_r1, bl1,
                                       nullptr, hbf, N, E);
    // layer 2: fused gather+MLP over h -> out (fp32)
    layer_k<0><<<LB, 256, 0, stream>>>(hbf, rowptrL, bsum, colA, Wb_l2, Wb_r2, bl2,
                                       out, nullptr, N, E);
}